// Round 1
// baseline (1764.453 us; speedup 1.0000x reference)
//
#include <hip/hip_runtime.h>
#include <math.h>

#define GAMMA 0.05f
#define EPSBN 1e-5f

#define B_   128
#define C1   3
#define H0   96
#define O1   32
#define H1C  92   // conv1 out spatial
#define P1   46   // pooled1
#define O2   64
#define H2C  42   // conv2 out spatial
#define P2   21   // pooled2
#define FLAT (O2*P2*P2)   // 28224
#define L1N  256
#define NCLS 10

// ---------------- wsq: per-output-channel ||w||^2 ----------------
__global__ void k_wsq(const float* __restrict__ w1, const float* __restrict__ w2,
                      float* __restrict__ wsq1, float* __restrict__ wsq2) {
    int t = threadIdx.x;
    if (t < 32) {
        const float* p = w1 + t * (C1 * 25);
        float s = 0.f;
        for (int i = 0; i < C1 * 25; ++i) s += p[i] * p[i];
        wsq1[t] = s;
    } else if (t < 96) {
        int o = t - 32;
        const float* p = w2 + (size_t)o * (O1 * 25);
        float s = 0.f;
        for (int i = 0; i < O1 * 25; ++i) s += p[i] * p[i];
        wsq2[o] = s;
    }
}

// ---------------- xsq1: conv(x*x, ones) over 3ch 5x5, out (B,92,92) ----------------
__global__ void k_xsq1(const float* __restrict__ x, float* __restrict__ xsq1) {
    int idx = blockIdx.x * blockDim.x + threadIdx.x;
    if (idx >= B_ * H1C * H1C) return;
    int j = idx % H1C;
    int t = idx / H1C;
    int i = t % H1C;
    int b = t / H1C;
    const float* xb = x + (size_t)b * C1 * H0 * H0;
    float s = 0.f;
    for (int c = 0; c < C1; ++c) {
        const float* xc = xb + (size_t)c * H0 * H0;
        #pragma unroll
        for (int ki = 0; ki < 5; ++ki) {
            const float* row = xc + (i + ki) * H0 + j;
            #pragma unroll
            for (int kj = 0; kj < 5; ++kj) { float v = row[kj]; s += v * v; }
        }
    }
    xsq1[idx] = s;
}

// ---------------- conv1 (RBF) + maxpool2 + relu + BN1 -> h1 (B,32,46,46) ----------------
__global__ void k_conv1(const float* __restrict__ x, const float* __restrict__ w1,
                        const float* __restrict__ xsq1, const float* __restrict__ wsq1,
                        const float* __restrict__ g, const float* __restrict__ bb_,
                        const float* __restrict__ m, const float* __restrict__ v,
                        float* __restrict__ h1) {
    int p = blockIdx.x * blockDim.x + threadIdx.x;
    if (p >= P1 * P1) return;
    int pj = p % P1, pi = p / P1;
    int o = blockIdx.y, b = blockIdx.z;

    const float* xb = x + (size_t)b * C1 * H0 * H0;
    const float* w = w1 + (size_t)o * C1 * 25;

    float cr00 = 0.f, cr01 = 0.f, cr10 = 0.f, cr11 = 0.f;
    for (int c = 0; c < C1; ++c) {
        float patch[6][6];
        const float* xc = xb + (size_t)c * H0 * H0 + (2 * pi) * H0 + 2 * pj;
        #pragma unroll
        for (int r = 0; r < 6; ++r)
            #pragma unroll
            for (int cc = 0; cc < 6; ++cc) patch[r][cc] = xc[r * H0 + cc];
        const float* wc = w + c * 25;
        #pragma unroll
        for (int ki = 0; ki < 5; ++ki)
            #pragma unroll
            for (int kj = 0; kj < 5; ++kj) {
                float wv = wc[ki * 5 + kj];
                cr00 = fmaf(patch[ki][kj],     wv, cr00);
                cr01 = fmaf(patch[ki][kj+1],   wv, cr01);
                cr10 = fmaf(patch[ki+1][kj],   wv, cr10);
                cr11 = fmaf(patch[ki+1][kj+1], wv, cr11);
            }
    }
    float wq = wsq1[o];
    const float* xs = xsq1 + (size_t)b * H1C * H1C + (2 * pi) * H1C + 2 * pj;
    float v00 = expf(-GAMMA * (xs[0]       - 2.f * cr00 + wq));
    float v01 = expf(-GAMMA * (xs[1]       - 2.f * cr01 + wq));
    float v10 = expf(-GAMMA * (xs[H1C]     - 2.f * cr10 + wq));
    float v11 = expf(-GAMMA * (xs[H1C + 1] - 2.f * cr11 + wq));
    float mx = fmaxf(fmaxf(v00, v01), fmaxf(v10, v11));
    mx = fmaxf(mx, 0.f);  // relu
    float sc = g[o] * rsqrtf(v[o] + EPSBN);
    float y = (mx - m[o]) * sc + bb_[o];
    h1[(((size_t)b * O1 + o) * P1 + pi) * P1 + pj] = y;
}

// ---------------- xsq2 over h1: (B,42,42), sum 32ch x 5x5 ----------------
__global__ void k_xsq2(const float* __restrict__ h1, float* __restrict__ xsq2) {
    int idx = blockIdx.x * blockDim.x + threadIdx.x;
    if (idx >= B_ * H2C * H2C) return;
    int j = idx % H2C;
    int t = idx / H2C;
    int i = t % H2C;
    int b = t / H2C;
    const float* hb = h1 + (size_t)b * O1 * P1 * P1;
    float s = 0.f;
    for (int c = 0; c < O1; ++c) {
        const float* hc = hb + (size_t)c * P1 * P1;
        #pragma unroll
        for (int ki = 0; ki < 5; ++ki) {
            const float* row = hc + (i + ki) * P1 + j;
            #pragma unroll
            for (int kj = 0; kj < 5; ++kj) { float vv = row[kj]; s += vv * vv; }
        }
    }
    xsq2[idx] = s;
}

// ---------------- conv2 (RBF) + maxpool2 + relu + BN2 -> h2 (B,64,21,21) ----------------
__global__ void k_conv2(const float* __restrict__ h1, const float* __restrict__ w2,
                        const float* __restrict__ xsq2, const float* __restrict__ wsq2,
                        const float* __restrict__ g, const float* __restrict__ bb_,
                        const float* __restrict__ m, const float* __restrict__ v,
                        float* __restrict__ h2) {
    int p = blockIdx.x * blockDim.x + threadIdx.x;
    if (p >= P2 * P2) return;
    int pj = p % P2, pi = p / P2;
    int o = blockIdx.y, b = blockIdx.z;

    const float* hb = h1 + (size_t)b * O1 * P1 * P1;
    const float* w = w2 + (size_t)o * O1 * 25;

    float cr00 = 0.f, cr01 = 0.f, cr10 = 0.f, cr11 = 0.f;
    for (int c = 0; c < O1; ++c) {
        float patch[6][6];
        const float* hc = hb + (size_t)c * P1 * P1 + (2 * pi) * P1 + 2 * pj;
        #pragma unroll
        for (int r = 0; r < 6; ++r)
            #pragma unroll
            for (int cc = 0; cc < 6; ++cc) patch[r][cc] = hc[r * P1 + cc];
        const float* wc = w + c * 25;
        #pragma unroll
        for (int ki = 0; ki < 5; ++ki)
            #pragma unroll
            for (int kj = 0; kj < 5; ++kj) {
                float wv = wc[ki * 5 + kj];
                cr00 = fmaf(patch[ki][kj],     wv, cr00);
                cr01 = fmaf(patch[ki][kj+1],   wv, cr01);
                cr10 = fmaf(patch[ki+1][kj],   wv, cr10);
                cr11 = fmaf(patch[ki+1][kj+1], wv, cr11);
            }
    }
    float wq = wsq2[o];
    const float* xs = xsq2 + (size_t)b * H2C * H2C + (2 * pi) * H2C + 2 * pj;
    float v00 = expf(-GAMMA * (xs[0]       - 2.f * cr00 + wq));
    float v01 = expf(-GAMMA * (xs[1]       - 2.f * cr01 + wq));
    float v10 = expf(-GAMMA * (xs[H2C]     - 2.f * cr10 + wq));
    float v11 = expf(-GAMMA * (xs[H2C + 1] - 2.f * cr11 + wq));
    float mx = fmaxf(fmaxf(v00, v01), fmaxf(v10, v11));
    mx = fmaxf(mx, 0.f);  // relu
    float sc = g[o] * rsqrtf(v[o] + EPSBN);
    float y = (mx - m[o]) * sc + bb_[o];
    h2[(((size_t)b * O2 + o) * P2 + pi) * P2 + pj] = y;
}

// ---------------- transpose fc1_w (256 x 28224) -> wt1 (28224 x 256) ----------------
__global__ void k_transpose(const float* __restrict__ in, float* __restrict__ out) {
    __shared__ float tile[32][33];
    int c0 = blockIdx.x * 32, r0 = blockIdx.y * 32;
    int tx = threadIdx.x & 31, ty = threadIdx.x >> 5;  // 32x8
    #pragma unroll
    for (int rr = ty; rr < 32; rr += 8)
        tile[rr][tx] = in[(size_t)(r0 + rr) * FLAT + c0 + tx];
    __syncthreads();
    #pragma unroll
    for (int rr = ty; rr < 32; rr += 8)
        out[(size_t)(c0 + rr) * L1N + r0 + tx] = tile[tx][rr];
}

// ---------------- FC1 partials: part[ks][b][o] ----------------
// grid (16 ksegs, 16 btiles), block 256 (=o). seg len 1764, btile 8.
__global__ void k_fc1(const float* __restrict__ A, const float* __restrict__ Wt,
                      float* __restrict__ part) {
    int o = threadIdx.x;
    int ks = blockIdx.x;
    int bt = blockIdx.y;
    int k0 = ks * 1764, b0 = bt * 8;
    float acc[8] = {0, 0, 0, 0, 0, 0, 0, 0};
    const float* wp = Wt + (size_t)k0 * L1N + o;
    for (int kk = 0; kk < 1764; kk += 4) {
        #pragma unroll
        for (int u = 0; u < 4; ++u) {
            float wv = wp[(size_t)(kk + u) * L1N];
            #pragma unroll
            for (int bbv = 0; bbv < 8; ++bbv)
                acc[bbv] = fmaf(wv, A[(size_t)(b0 + bbv) * FLAT + k0 + kk + u], acc[bbv]);
        }
    }
    float* pp = part + ((size_t)ks * B_ + b0) * L1N + o;
    #pragma unroll
    for (int bbv = 0; bbv < 8; ++bbv) pp[(size_t)bbv * L1N] = acc[bbv];
}

// ---------------- FC1 reduce + bias + relu ----------------
__global__ void k_fc1red(const float* __restrict__ part, const float* __restrict__ bias,
                         float* __restrict__ fc1o) {
    int idx = blockIdx.x * blockDim.x + threadIdx.x;
    if (idx >= B_ * L1N) return;
    int o = idx & (L1N - 1);
    float s = 0.f;
    #pragma unroll
    for (int ks = 0; ks < 16; ++ks) s += part[(size_t)ks * B_ * L1N + idx];
    fc1o[idx] = fmaxf(s + bias[o], 0.f);
}

// ---------------- FC2 + relu + log_softmax ----------------
__global__ void k_fc2(const float* __restrict__ a, const float* __restrict__ w,
                      const float* __restrict__ bias, float* __restrict__ out) {
    int b = blockIdx.x;
    int lane = threadIdx.x;  // 64
    __shared__ float z[NCLS];
    for (int j = 0; j < NCLS; ++j) {
        float p = 0.f;
        for (int k = lane; k < L1N; k += 64)
            p = fmaf(a[(size_t)b * L1N + k], w[(size_t)j * L1N + k], p);
        #pragma unroll
        for (int off = 32; off; off >>= 1) p += __shfl_down(p, off, 64);
        if (lane == 0) z[j] = fmaxf(p + bias[j], 0.f);
    }
    __syncthreads();
    if (lane == 0) {
        float mx = -1e30f;
        for (int j = 0; j < NCLS; ++j) mx = fmaxf(mx, z[j]);
        float s = 0.f;
        for (int j = 0; j < NCLS; ++j) s += expf(z[j] - mx);
        float l = logf(s);
        for (int j = 0; j < NCLS; ++j) out[(size_t)b * NCLS + j] = z[j] - mx - l;
    }
}

extern "C" void kernel_launch(void* const* d_in, const int* in_sizes, int n_in,
                              void* d_out, int out_size, void* d_ws, size_t ws_size,
                              hipStream_t stream) {
    const float* x    = (const float*)d_in[0];
    const float* w1   = (const float*)d_in[1];
    const float* w2   = (const float*)d_in[2];
    const float* bn1g = (const float*)d_in[3];
    const float* bn1b = (const float*)d_in[4];
    const float* bn1m = (const float*)d_in[5];
    const float* bn1v = (const float*)d_in[6];
    const float* bn2g = (const float*)d_in[7];
    const float* bn2b = (const float*)d_in[8];
    const float* bn2m = (const float*)d_in[9];
    const float* bn2v = (const float*)d_in[10];
    const float* fc1w = (const float*)d_in[11];
    const float* fc1b = (const float*)d_in[12];
    const float* fc2w = (const float*)d_in[13];
    const float* fc2b = (const float*)d_in[14];
    float* out = (float*)d_out;

    float* ws = (float*)d_ws;
    size_t off = 0;
    float* xsq1 = ws + off; off += (size_t)B_ * H1C * H1C;        // 1,083,392
    float* h1   = ws + off; off += (size_t)B_ * O1 * P1 * P1;     // 8,667,136
    float* xsq2 = ws + off; off += (size_t)B_ * H2C * H2C;        // 225,792
    float* h2   = ws + off; off += (size_t)B_ * O2 * P2 * P2;     // 3,612,672
    float* wt1  = ws + off; off += (size_t)FLAT * L1N;            // 7,225,344
    float* part = ws + off; off += (size_t)16 * B_ * L1N;         // 524,288
    float* fc1o = ws + off; off += (size_t)B_ * L1N;              // 32,768
    float* wsq1 = ws + off; off += 32;
    float* wsq2 = ws + off; off += 64;

    k_wsq<<<1, 128, 0, stream>>>(w1, w2, wsq1, wsq2);
    k_transpose<<<dim3(FLAT / 32, L1N / 32), 256, 0, stream>>>(fc1w, wt1);
    k_xsq1<<<(B_ * H1C * H1C + 255) / 256, 256, 0, stream>>>(x, xsq1);
    k_conv1<<<dim3((P1 * P1 + 255) / 256, O1, B_), 256, 0, stream>>>(
        x, w1, xsq1, wsq1, bn1g, bn1b, bn1m, bn1v, h1);
    k_xsq2<<<(B_ * H2C * H2C + 255) / 256, 256, 0, stream>>>(h1, xsq2);
    k_conv2<<<dim3((P2 * P2 + 255) / 256, O2, B_), 256, 0, stream>>>(
        h1, w2, xsq2, wsq2, bn2g, bn2b, bn2m, bn2v, h2);
    k_fc1<<<dim3(16, 16), 256, 0, stream>>>(h2, wt1, part);
    k_fc1red<<<(B_ * L1N + 255) / 256, 256, 0, stream>>>(part, fc1b, fc1o);
    k_fc2<<<B_, 64, 0, stream>>>(fc1o, fc2w, fc2b, out);
}

// Round 2
// 290.641 us; speedup vs baseline: 6.0709x; 6.0709x over previous
//
#include <hip/hip_runtime.h>
#include <math.h>

#define GAMMA 0.05f
#define EPSBN 1e-5f

#define B_   128
#define C1   3
#define H0   96
#define O1   32
#define P1   46   // pooled1 (46x46), conv1 out 92x92
#define O2   64
#define H2C  42   // conv2 out spatial
#define P2   21   // pooled2
#define FLAT (O2*P2*P2)   // 28224
#define L1N  256
#define NCLS 10

typedef __attribute__((ext_vector_type(8))) short bf16x8;
typedef __attribute__((ext_vector_type(4))) float f32x4;

static __device__ __forceinline__ float bf2f(unsigned short h) {
    return __uint_as_float(((unsigned int)h) << 16);
}
static __device__ __forceinline__ unsigned short f2bf(float f) {
    unsigned int u = __float_as_uint(f);
    u = (u + 0x7FFFu + ((u >> 16) & 1u)) >> 16;
    return (unsigned short)u;
}

// ---------------- prep: wsq1, wsq2, w2bf[kp][o][c] bf16 ----------------
__global__ void k_prep(const float* __restrict__ w1, const float* __restrict__ w2,
                       float* __restrict__ wsq1, float* __restrict__ wsq2,
                       unsigned short* __restrict__ w2bf) {
    int t = blockIdx.x * 256 + threadIdx.x;
    for (int i = t; i < 25 * 64 * 32; i += gridDim.x * 256) {
        int c = i & 31;
        int o = (i >> 5) & 63;
        int kp = i >> 11;
        w2bf[i] = f2bf(w2[(size_t)(o * 32 + c) * 25 + kp]);
    }
    if (blockIdx.x == 0) {
        int lt = threadIdx.x;
        if (lt < 32) {
            const float* p = w1 + lt * 75;
            float s = 0.f;
            for (int i = 0; i < 75; ++i) s += p[i] * p[i];
            wsq1[lt] = s;
        } else if (lt < 96) {
            const float* p = w2 + (size_t)(lt - 32) * 800;
            float s = 0.f;
            for (int i = 0; i < 800; ++i) s += p[i] * p[i];
            wsq2[lt - 32] = s;
        }
    }
}

// ------- wt1[p][o][n] = fc1w[n][o*441+p]  (permuted transpose, fp32) -------
__global__ void k_tr1(const float* __restrict__ in, float* __restrict__ out) {
    __shared__ float tile[32][33];
    int p0 = blockIdx.x * 32, n0 = blockIdx.y * 32, o = blockIdx.z;
    int tx = threadIdx.x & 31, ty = threadIdx.x >> 5;  // 32x8
    #pragma unroll
    for (int rr = ty; rr < 32; rr += 8) {
        int p = p0 + tx;
        tile[rr][tx] = (p < 441) ? in[(size_t)(n0 + rr) * FLAT + o * 441 + p] : 0.f;
    }
    __syncthreads();
    #pragma unroll
    for (int rr = ty; rr < 32; rr += 8) {
        int p = p0 + rr;
        if (p < 441)
            out[((size_t)p * 64 + o) * L1N + n0 + tx] = tile[tx][rr];
    }
}

// ------- conv1 (RBF) + pool + relu + BN1 -> h1t [b][46][46][32] bf16 -------
// one thread per pooled position, all 32 output channels, xsq inline
__global__ __launch_bounds__(256) void k_conv1(
    const float* __restrict__ x, const float* __restrict__ w1,
    const float* __restrict__ wsq1,
    const float* __restrict__ g, const float* __restrict__ bb_,
    const float* __restrict__ m, const float* __restrict__ v,
    unsigned short* __restrict__ h1t) {
    int p = blockIdx.x * 256 + threadIdx.x;
    if (p >= P1 * P1) return;
    int b = blockIdx.y;
    int pi = p / P1, pj = p % P1;
    const float* xb = x + (size_t)b * C1 * H0 * H0 + (2 * pi) * H0 + 2 * pj;

    float xq0 = 0.f, xq1 = 0.f, xq2 = 0.f, xq3 = 0.f;
    #pragma unroll 1
    for (int oc = 0; oc < 4; ++oc) {
        float cr[8][4];
        #pragma unroll
        for (int o8 = 0; o8 < 8; ++o8)
            #pragma unroll
            for (int r = 0; r < 4; ++r) cr[o8][r] = 0.f;
        for (int c = 0; c < 3; ++c) {
            float patch[6][6];
            const float* xc = xb + (size_t)c * H0 * H0;
            #pragma unroll
            for (int r = 0; r < 6; ++r)
                #pragma unroll
                for (int cc = 0; cc < 6; ++cc) patch[r][cc] = xc[r * H0 + cc];
            if (oc == 0) {
                #pragma unroll
                for (int ki = 0; ki < 5; ++ki)
                    #pragma unroll
                    for (int kj = 0; kj < 5; ++kj) {
                        xq0 = fmaf(patch[ki][kj],     patch[ki][kj],     xq0);
                        xq1 = fmaf(patch[ki][kj+1],   patch[ki][kj+1],   xq1);
                        xq2 = fmaf(patch[ki+1][kj],   patch[ki+1][kj],   xq2);
                        xq3 = fmaf(patch[ki+1][kj+1], patch[ki+1][kj+1], xq3);
                    }
            }
            #pragma unroll
            for (int o8 = 0; o8 < 8; ++o8) {
                const float* wc = w1 + (size_t)((oc * 8 + o8) * 3 + c) * 25;
                #pragma unroll
                for (int ki = 0; ki < 5; ++ki)
                    #pragma unroll
                    for (int kj = 0; kj < 5; ++kj) {
                        float wv = wc[ki * 5 + kj];
                        cr[o8][0] = fmaf(patch[ki][kj],     wv, cr[o8][0]);
                        cr[o8][1] = fmaf(patch[ki][kj+1],   wv, cr[o8][1]);
                        cr[o8][2] = fmaf(patch[ki+1][kj],   wv, cr[o8][2]);
                        cr[o8][3] = fmaf(patch[ki+1][kj+1], wv, cr[o8][3]);
                    }
            }
        }
        unsigned short ob[8];
        #pragma unroll
        for (int o8 = 0; o8 < 8; ++o8) {
            int o = oc * 8 + o8;
            float wq = wsq1[o];
            float e0 = __expf(-GAMMA * (xq0 - 2.f * cr[o8][0] + wq));
            float e1 = __expf(-GAMMA * (xq1 - 2.f * cr[o8][1] + wq));
            float e2 = __expf(-GAMMA * (xq2 - 2.f * cr[o8][2] + wq));
            float e3 = __expf(-GAMMA * (xq3 - 2.f * cr[o8][3] + wq));
            float mx = fmaxf(fmaxf(e0, e1), fmaxf(e2, e3));
            float sc = g[o] * rsqrtf(v[o] + EPSBN);
            float y = (mx - m[o]) * sc + bb_[o];
            ob[o8] = f2bf(y);
        }
        uint4 pk;
        pk.x = (unsigned)ob[0] | ((unsigned)ob[1] << 16);
        pk.y = (unsigned)ob[2] | ((unsigned)ob[3] << 16);
        pk.z = (unsigned)ob[4] | ((unsigned)ob[5] << 16);
        pk.w = (unsigned)ob[6] | ((unsigned)ob[7] << 16);
        *(uint4*)(h1t + ((size_t)b * 2116 + p) * 32 + oc * 8) = pk;
    }
}

// ---------------- ssum[b][y][x] = sum_c h1t^2 ----------------
__global__ void k_ssum(const unsigned short* __restrict__ h1t, float* __restrict__ ssum) {
    int idx = blockIdx.x * 256 + threadIdx.x;
    if (idx >= B_ * 2116) return;
    const uint4* p = (const uint4*)(h1t + (size_t)idx * 32);
    float s = 0.f;
    #pragma unroll
    for (int q = 0; q < 4; ++q) {
        uint4 u = p[q];
        unsigned int w_[4] = {u.x, u.y, u.z, u.w};
        #pragma unroll
        for (int k = 0; k < 4; ++k) {
            float a = __uint_as_float(w_[k] << 16);
            float b = __uint_as_float(w_[k] & 0xFFFF0000u);
            s = fmaf(a, a, s);
            s = fmaf(b, b, s);
        }
    }
    ssum[idx] = s;
}

// ---------------- xsq2[b][i][j] = 5x5 box sum of ssum ----------------
__global__ void k_xsq2s(const float* __restrict__ ssum, float* __restrict__ xsq2) {
    int idx = blockIdx.x * 256 + threadIdx.x;
    if (idx >= B_ * H2C * H2C) return;
    int j = idx % H2C;
    int t = idx / H2C;
    int i = t % H2C;
    int b = t / H2C;
    const float* s = ssum + ((size_t)b * P1 + i) * P1 + j;
    float acc = 0.f;
    #pragma unroll
    for (int ki = 0; ki < 5; ++ki)
        #pragma unroll
        for (int kj = 0; kj < 5; ++kj) acc += s[ki * P1 + kj];
    xsq2[idx] = acc;
}

// ------- conv2 MFMA: 25 shifted GEMMs K=32, fused exp/pool/BN2 -------
// h2t [b][441][64] bf16
__global__ __launch_bounds__(512, 1) void k_conv2m(
    const unsigned short* __restrict__ h1t, const unsigned short* __restrict__ w2bf,
    const float* __restrict__ xsq2, const float* __restrict__ wsq2,
    const float* __restrict__ g2, const float* __restrict__ b2,
    const float* __restrict__ m2, const float* __restrict__ v2,
    unsigned short* __restrict__ h2t) {
    __shared__ unsigned short lds[26 * 46 * 32];  // 76544 B
    int b = blockIdx.y, half = blockIdx.x;
    int r0 = half ? 22 : 0;
    int nrows = half ? 24 : 26;
    int tid = threadIdx.x;
    {
        const uint4* src = (const uint4*)(h1t + ((size_t)b * 46 + r0) * 46 * 32);
        uint4* dst = (uint4*)lds;
        int n16 = nrows * 46 * 32 / 8;
        for (int i = tid; i < n16; i += 512) dst[i] = src[i];
    }
    __syncthreads();

    int lane = tid & 63, wv = tid >> 6;
    int l15 = lane & 15, l4 = lane >> 4;
    int otile = wv & 3, mh = wv >> 2;
    int o = otile * 16 + l15;

    bf16x8 Bf[25];
    #pragma unroll
    for (int kp = 0; kp < 25; ++kp)
        Bf[kp] = *(const bf16x8*)(w2bf + ((size_t)kp * 64 + o) * 32 + l4 * 8);

    float wq = wsq2[o];
    float sc = g2[o] * rsqrtf(v2[o] + EPSBN);
    float mo = m2[o], bo = b2[o];

    int prS = half ? 11 : 0, prE = half ? 21 : 11;
    for (int pr = prS + mh; pr < prE; pr += 2) {
        int il = 2 * pr - r0 + (l15 & 1);
        for (int jt = 0; jt < 6; ++jt) {
            int j0 = (jt < 5) ? jt * 8 : 34;
            int jl = j0 + (l15 >> 1);
            const unsigned short* ab = lds + ((size_t)il * 46 + jl) * 32 + l4 * 8;
            f32x4 acc = {0.f, 0.f, 0.f, 0.f};
            #pragma unroll
            for (int ki = 0; ki < 5; ++ki)
                #pragma unroll
                for (int kj = 0; kj < 5; ++kj) {
                    bf16x8 av = *(const bf16x8*)(ab + (ki * 46 + kj) * 32);
                    acc = __builtin_amdgcn_mfma_f32_16x16x32_bf16(av, Bf[ki * 5 + kj], acc, 0, 0, 0);
                }
            const float* xs = xsq2 + ((size_t)b * H2C + 2 * pr) * H2C + (j0 + 2 * l4);
            float e0 = __expf(-GAMMA * (xs[0]       - 2.f * acc[0] + wq));
            float e1 = __expf(-GAMMA * (xs[H2C]     - 2.f * acc[1] + wq));
            float e2 = __expf(-GAMMA * (xs[1]       - 2.f * acc[2] + wq));
            float e3 = __expf(-GAMMA * (xs[H2C + 1] - 2.f * acc[3] + wq));
            float mx = fmaxf(fmaxf(e0, e1), fmaxf(e2, e3));
            float y = (mx - mo) * sc + bo;
            h2t[((size_t)b * 441 + pr * 21 + (j0 >> 1) + l4) * 64 + o] = f2bf(y);
        }
    }
}

// ---------------- FC1 partials: part[ks][b][o], 32 ksegs x 8 btiles ----------------
__global__ __launch_bounds__(256) void k_fc1(const unsigned short* __restrict__ A,
                                             const float* __restrict__ Wt,
                                             float* __restrict__ part) {
    __shared__ float As[16 * 882];  // 56448 B
    int o = threadIdx.x;
    int ks = blockIdx.x, bt = blockIdx.y;
    int k0 = ks * 882, b0 = bt * 16;
    for (int i = threadIdx.x; i < 16 * 882; i += 256) {
        int bb = i / 882, kk = i - bb * 882;
        As[i] = bf2f(A[(size_t)(b0 + bb) * FLAT + k0 + kk]);
    }
    __syncthreads();
    float acc[16];
    #pragma unroll
    for (int bb = 0; bb < 16; ++bb) acc[bb] = 0.f;
    const float* wp = Wt + (size_t)k0 * L1N + o;
    for (int kk = 0; kk < 882; ++kk) {
        float wvv = wp[(size_t)kk * L1N];
        #pragma unroll
        for (int bb = 0; bb < 16; ++bb)
            acc[bb] = fmaf(wvv, As[bb * 882 + kk], acc[bb]);
    }
    float* pp = part + ((size_t)ks * B_ + b0) * L1N + o;
    #pragma unroll
    for (int bb = 0; bb < 16; ++bb) pp[(size_t)bb * L1N] = acc[bb];
}

// ---------------- FC1 reduce + bias + relu ----------------
__global__ void k_fc1red(const float* __restrict__ part, const float* __restrict__ bias,
                         float* __restrict__ fc1o) {
    int idx = blockIdx.x * blockDim.x + threadIdx.x;
    if (idx >= B_ * L1N) return;
    int o = idx & (L1N - 1);
    float s = 0.f;
    #pragma unroll
    for (int ks = 0; ks < 32; ++ks) s += part[(size_t)ks * B_ * L1N + idx];
    fc1o[idx] = fmaxf(s + bias[o], 0.f);
}

// ---------------- FC2 + relu + log_softmax ----------------
__global__ void k_fc2(const float* __restrict__ a, const float* __restrict__ w,
                      const float* __restrict__ bias, float* __restrict__ out) {
    int b = blockIdx.x;
    int lane = threadIdx.x;  // 64
    __shared__ float z[NCLS];
    for (int j = 0; j < NCLS; ++j) {
        float p = 0.f;
        for (int k = lane; k < L1N; k += 64)
            p = fmaf(a[(size_t)b * L1N + k], w[(size_t)j * L1N + k], p);
        #pragma unroll
        for (int off = 32; off; off >>= 1) p += __shfl_down(p, off, 64);
        if (lane == 0) z[j] = fmaxf(p + bias[j], 0.f);
    }
    __syncthreads();
    if (lane == 0) {
        float mx = -1e30f;
        for (int j = 0; j < NCLS; ++j) mx = fmaxf(mx, z[j]);
        float s = 0.f;
        for (int j = 0; j < NCLS; ++j) s += expf(z[j] - mx);
        float l = logf(s);
        for (int j = 0; j < NCLS; ++j) out[(size_t)b * NCLS + j] = z[j] - mx - l;
    }
}

extern "C" void kernel_launch(void* const* d_in, const int* in_sizes, int n_in,
                              void* d_out, int out_size, void* d_ws, size_t ws_size,
                              hipStream_t stream) {
    const float* x    = (const float*)d_in[0];
    const float* w1   = (const float*)d_in[1];
    const float* w2   = (const float*)d_in[2];
    const float* bn1g = (const float*)d_in[3];
    const float* bn1b = (const float*)d_in[4];
    const float* bn1m = (const float*)d_in[5];
    const float* bn1v = (const float*)d_in[6];
    const float* bn2g = (const float*)d_in[7];
    const float* bn2b = (const float*)d_in[8];
    const float* bn2m = (const float*)d_in[9];
    const float* bn2v = (const float*)d_in[10];
    const float* fc1w = (const float*)d_in[11];
    const float* fc1b = (const float*)d_in[12];
    const float* fc2w = (const float*)d_in[13];
    const float* fc2b = (const float*)d_in[14];
    float* out = (float*)d_out;

    char* wsb = (char*)d_ws;
    unsigned short* h1t = (unsigned short*)wsb; wsb += (size_t)B_ * 2116 * 32 * 2;   // 17.3 MB
    float* ssum = (float*)wsb;                  wsb += (size_t)B_ * 2116 * 4;        // 1.08 MB
    float* xsq2 = (float*)wsb;                  wsb += (size_t)B_ * H2C * H2C * 4;   // 0.90 MB
    unsigned short* h2t = (unsigned short*)wsb; wsb += (size_t)B_ * FLAT * 2;        // 7.2 MB
    float* wt1 = (float*)wsb;                   wsb += (size_t)441 * 64 * L1N * 4;   // 28.9 MB
    float* part = (float*)wsb;                  wsb += (size_t)32 * B_ * L1N * 4;    // 4.2 MB
    float* fc1o = (float*)wsb;                  wsb += (size_t)B_ * L1N * 4;
    unsigned short* w2bf = (unsigned short*)wsb; wsb += (size_t)25 * 64 * 32 * 2;
    float* wsq1 = (float*)wsb;                  wsb += 32 * 4;
    float* wsq2 = (float*)wsb;                  wsb += 64 * 4;

    k_prep<<<200, 256, 0, stream>>>(w1, w2, wsq1, wsq2, w2bf);
    k_tr1<<<dim3(14, 8, 64), 256, 0, stream>>>(fc1w, wt1);
    k_conv1<<<dim3((P1 * P1 + 255) / 256, B_), 256, 0, stream>>>(
        x, w1, wsq1, bn1g, bn1b, bn1m, bn1v, h1t);
    k_ssum<<<(B_ * 2116 + 255) / 256, 256, 0, stream>>>(h1t, ssum);
    k_xsq2s<<<(B_ * H2C * H2C + 255) / 256, 256, 0, stream>>>(ssum, xsq2);
    k_conv2m<<<dim3(2, B_), 512, 0, stream>>>(
        h1t, w2bf, xsq2, wsq2, bn2g, bn2b, bn2m, bn2v, h2t);
    k_fc1<<<dim3(32, 8), 256, 0, stream>>>(h2t, wt1, part);
    k_fc1red<<<(B_ * L1N + 255) / 256, 256, 0, stream>>>(part, fc1b, fc1o);
    k_fc2<<<B_, 64, 0, stream>>>(fc1o, fc2w, fc2b, out);
}

// Round 3
// 151.711 us; speedup vs baseline: 11.6304x; 1.9158x over previous
//
#include <hip/hip_runtime.h>
#include <math.h>

#define GAMMA 0.05f
#define EPSBN 1e-5f

#define B_   128
#define H0   96
#define O1   32
#define P1   46   // pooled1 (46x46), conv1 out 92x92
#define O2   64
#define H2C  42   // conv2 out spatial
#define P2   21   // pooled2
#define FLAT (O2*P2*P2)   // 28224
#define L1N  256
#define NCLS 10
#define XW   104  // padded x8 row width

typedef __attribute__((ext_vector_type(8))) short bf16x8;
typedef __attribute__((ext_vector_type(4))) float f32x4;

static __device__ __forceinline__ float bf2f(unsigned short h) {
    return __uint_as_float(((unsigned int)h) << 16);
}
static __device__ __forceinline__ unsigned short f2bf(float f) {
    unsigned int u = __float_as_uint(f);
    u = (u + 0x7FFFu + ((u >> 16) & 1u)) >> 16;
    return (unsigned short)u;
}

// ------- prep: w2bf[kp][o][c], w1p8[t][o][8ch], wsq1, wsq2 -------
__global__ void k_prep(const float* __restrict__ w1, const float* __restrict__ w2,
                       float* __restrict__ wsq1, float* __restrict__ wsq2,
                       unsigned short* __restrict__ w2bf, unsigned short* __restrict__ w1p8) {
    int t0 = blockIdx.x * 256 + threadIdx.x;
    for (int i = t0; i < 25 * 64 * 32 + 28 * 32 * 8; i += gridDim.x * 256) {
        if (i < 25 * 64 * 32) {
            int c = i & 31, o = (i >> 5) & 63, kp = i >> 11;
            w2bf[i] = f2bf(w2[(size_t)(o * 32 + c) * 25 + kp]);
        } else {
            int j = i - 25 * 64 * 32;
            int ch = j & 7, o = (j >> 3) & 31, t = j >> 8;  // t 0..27
            float v = (t < 25 && ch < 3) ? w1[(size_t)(o * 3 + ch) * 25 + t] : 0.f;
            w1p8[j] = f2bf(v);
        }
    }
    if (blockIdx.x == 0) {
        int lt = threadIdx.x;
        if (lt < 32) {
            const float* p = w1 + lt * 75;
            float s = 0.f;
            for (int i = 0; i < 75; ++i) s += p[i] * p[i];
            wsq1[lt] = s;
        } else if (lt < 96) {
            const float* p = w2 + (size_t)(lt - 32) * 800;
            float s = 0.f;
            for (int i = 0; i < 800; ++i) s += p[i] * p[i];
            wsq2[lt - 32] = s;
        }
    }
}

// ------- x8[b][r][cc][8] bf16: channels 0..2 + zero pad; zero cols >= 96 -------
__global__ void k_x8(const float* __restrict__ x, unsigned short* __restrict__ x8) {
    int idx = blockIdx.x * 256 + threadIdx.x;
    if (idx >= B_ * H0 * XW) return;
    int cc = idx % XW;
    int t = idx / XW;
    int r = t % H0, b = t / H0;
    unsigned int p0 = 0, p1 = 0, p2 = 0, p3 = 0;
    if (cc < 96) {
        const float* xp = x + (size_t)b * 3 * 9216 + r * 96 + cc;
        p0 = (unsigned)f2bf(xp[0]) | ((unsigned)f2bf(xp[9216]) << 16);
        p1 = (unsigned)f2bf(xp[18432]);
    }
    uint4 pk; pk.x = p0; pk.y = p1; pk.z = p2; pk.w = p3;
    *(uint4*)(x8 + (size_t)idx * 8) = pk;
}

// ------- ssum1[b][96][96] = sum_c x^2 (fp32, exact path for xsq) -------
__global__ void k_ssum1(const float* __restrict__ x, float* __restrict__ ssum1) {
    int idx = blockIdx.x * 256 + threadIdx.x;
    if (idx >= B_ * 9216) return;
    int b = idx / 9216, r = idx % 9216;
    const float* xp = x + (size_t)b * 27648 + r;
    float a = xp[0], c = xp[9216], d = xp[18432];
    ssum1[idx] = a * a + c * c + d * d;
}

// ------- xsq1[b][92][92] = 5x5 box sum of ssum1 -------
__global__ void k_xsq1b(const float* __restrict__ ssum1, float* __restrict__ xsq1) {
    int idx = blockIdx.x * 256 + threadIdx.x;
    if (idx >= B_ * 92 * 92) return;
    int j = idx % 92;
    int t = idx / 92;
    int i = t % 92, b = t / 92;
    const float* s = ssum1 + (size_t)b * 9216 + i * 96 + j;
    float acc = 0.f;
    #pragma unroll
    for (int ki = 0; ki < 5; ++ki)
        #pragma unroll
        for (int kj = 0; kj < 5; ++kj) acc += s[ki * 96 + kj];
    xsq1[idx] = acc;
}

// ------- conv1 MFMA: 7 MFMAs (4 taps x 8ch each) per row, fused exp/pool/BN1 -------
// h1t [b][46*46][32] bf16
__global__ __launch_bounds__(256) void k_conv1m(
    const unsigned short* __restrict__ x8, const unsigned short* __restrict__ w1p8,
    const float* __restrict__ xsq1, const float* __restrict__ wsq1,
    const float* __restrict__ g, const float* __restrict__ bb_,
    const float* __restrict__ m, const float* __restrict__ v,
    unsigned short* __restrict__ h1t) {
    __shared__ unsigned short xt[13 * XW * 8];  // 21632 B
    int b = blockIdx.y;
    int pi0 = blockIdx.x * 4;
    int tid = threadIdx.x;
    for (int idx = tid; idx < 13 * XW; idx += 256) {
        int rr = idx / XW, cc = idx % XW;
        int srow = 2 * pi0 + rr; if (srow > 95) srow = 95;
        *(uint4*)(xt + (size_t)idx * 8) =
            *(const uint4*)(x8 + (((size_t)b * H0 + srow) * XW + cc) * 8);
    }
    __syncthreads();
    int w = tid >> 6, lane = tid & 63;
    int pi = pi0 + w;
    if (pi >= P1) return;
    int l15 = lane & 15, l4 = lane >> 4;

    bf16x8 Bf[7][2];
    int kio[7], kjo[7];
    #pragma unroll
    for (int mm = 0; mm < 7; ++mm) {
        int t = mm * 4 + l4;  // 0..27
        kio[mm] = t / 5; kjo[mm] = t - kio[mm] * 5;
        #pragma unroll
        for (int nt = 0; nt < 2; ++nt)
            Bf[mm][nt] = *(const bf16x8*)(w1p8 + ((size_t)t * 32 + nt * 16 + l15) * 8);
    }
    float wqa[2], sca[2], moa[2], boa[2];
    #pragma unroll
    for (int nt = 0; nt < 2; ++nt) {
        int o = nt * 16 + l15;
        wqa[nt] = wsq1[o];
        sca[nt] = g[o] * rsqrtf(v[o] + EPSBN);
        moa[nt] = m[o]; boa[nt] = bb_[o];
    }

    for (int s6 = 0; s6 < 6; ++s6) {
        int j0 = s6 * 16;
        f32x4 a0[2], a1[2];
        #pragma unroll
        for (int nt = 0; nt < 2; ++nt) {
            a0[nt] = (f32x4){0.f, 0.f, 0.f, 0.f};
            a1[nt] = (f32x4){0.f, 0.f, 0.f, 0.f};
        }
        {
            int ri = 2 * w;
            #pragma unroll
            for (int mm = 0; mm < 7; ++mm) {
                bf16x8 av = *(const bf16x8*)(xt + ((size_t)(ri + kio[mm]) * XW + j0 + l15 + kjo[mm]) * 8);
                a0[0] = __builtin_amdgcn_mfma_f32_16x16x32_bf16(av, Bf[mm][0], a0[0], 0, 0, 0);
                a0[1] = __builtin_amdgcn_mfma_f32_16x16x32_bf16(av, Bf[mm][1], a0[1], 0, 0, 0);
            }
            ri = 2 * w + 1;
            #pragma unroll
            for (int mm = 0; mm < 7; ++mm) {
                bf16x8 av = *(const bf16x8*)(xt + ((size_t)(ri + kio[mm]) * XW + j0 + l15 + kjo[mm]) * 8);
                a1[0] = __builtin_amdgcn_mfma_f32_16x16x32_bf16(av, Bf[mm][0], a1[0], 0, 0, 0);
                a1[1] = __builtin_amdgcn_mfma_f32_16x16x32_bf16(av, Bf[mm][1], a1[1], 0, 0, 0);
            }
        }
        int i0 = 2 * pi;
        #pragma unroll
        for (int q = 0; q < 2; ++q) {
            int jc = j0 + l4 * 4 + 2 * q;      // conv col of left pool element
            int pj = (j0 >> 1) + l4 * 2 + q;   // pooled col
            if (pj < P1) {
                const float* xr = xsq1 + ((size_t)b * 92 + i0) * 92 + jc;
                float xv00 = xr[0], xv01 = xr[1], xv10 = xr[92], xv11 = xr[93];
                #pragma unroll
                for (int nt = 0; nt < 2; ++nt) {
                    float e00 = __expf(-GAMMA * (xv00 - 2.f * a0[nt][2 * q]     + wqa[nt]));
                    float e01 = __expf(-GAMMA * (xv01 - 2.f * a0[nt][2 * q + 1] + wqa[nt]));
                    float e10 = __expf(-GAMMA * (xv10 - 2.f * a1[nt][2 * q]     + wqa[nt]));
                    float e11 = __expf(-GAMMA * (xv11 - 2.f * a1[nt][2 * q + 1] + wqa[nt]));
                    float mx = fmaxf(fmaxf(e00, e01), fmaxf(e10, e11));
                    float y = (mx - moa[nt]) * sca[nt] + boa[nt];
                    h1t[((size_t)b * 2116 + pi * P1 + pj) * 32 + nt * 16 + l15] = f2bf(y);
                }
            }
        }
    }
}

// ---------------- ssum[b][y][x] = sum_c h1t^2 ----------------
__global__ void k_ssum(const unsigned short* __restrict__ h1t, float* __restrict__ ssum) {
    int idx = blockIdx.x * 256 + threadIdx.x;
    if (idx >= B_ * 2116) return;
    const uint4* p = (const uint4*)(h1t + (size_t)idx * 32);
    float s = 0.f;
    #pragma unroll
    for (int q = 0; q < 4; ++q) {
        uint4 u = p[q];
        unsigned int w_[4] = {u.x, u.y, u.z, u.w};
        #pragma unroll
        for (int k = 0; k < 4; ++k) {
            float a = __uint_as_float(w_[k] << 16);
            float b = __uint_as_float(w_[k] & 0xFFFF0000u);
            s = fmaf(a, a, s);
            s = fmaf(b, b, s);
        }
    }
    ssum[idx] = s;
}

// ---------------- xsq2[b][i][j] = 5x5 box sum of ssum ----------------
__global__ void k_xsq2s(const float* __restrict__ ssum, float* __restrict__ xsq2) {
    int idx = blockIdx.x * 256 + threadIdx.x;
    if (idx >= B_ * H2C * H2C) return;
    int j = idx % H2C;
    int t = idx / H2C;
    int i = t % H2C;
    int b = t / H2C;
    const float* s = ssum + ((size_t)b * P1 + i) * P1 + j;
    float acc = 0.f;
    #pragma unroll
    for (int ki = 0; ki < 5; ++ki)
        #pragma unroll
        for (int kj = 0; kj < 5; ++kj) acc += s[ki * P1 + kj];
    xsq2[idx] = acc;
}

// ------- conv2 MFMA: 25 shifted GEMMs K=32, fused exp/pool/BN2 -------
__global__ __launch_bounds__(512, 1) void k_conv2m(
    const unsigned short* __restrict__ h1t, const unsigned short* __restrict__ w2bf,
    const float* __restrict__ xsq2, const float* __restrict__ wsq2,
    const float* __restrict__ g2, const float* __restrict__ b2,
    const float* __restrict__ m2, const float* __restrict__ v2,
    unsigned short* __restrict__ h2t) {
    __shared__ unsigned short lds[26 * 46 * 32];  // 76544 B
    int b = blockIdx.y, half = blockIdx.x;
    int r0 = half ? 22 : 0;
    int nrows = half ? 24 : 26;
    int tid = threadIdx.x;
    {
        const uint4* src = (const uint4*)(h1t + ((size_t)b * 46 + r0) * 46 * 32);
        uint4* dst = (uint4*)lds;
        int n16 = nrows * 46 * 32 / 8;
        for (int i = tid; i < n16; i += 512) dst[i] = src[i];
    }
    __syncthreads();

    int lane = tid & 63, wv = tid >> 6;
    int l15 = lane & 15, l4 = lane >> 4;
    int otile = wv & 3, mh = wv >> 2;
    int o = otile * 16 + l15;

    bf16x8 Bf[25];
    #pragma unroll
    for (int kp = 0; kp < 25; ++kp)
        Bf[kp] = *(const bf16x8*)(w2bf + ((size_t)kp * 64 + o) * 32 + l4 * 8);

    float wq = wsq2[o];
    float sc = g2[o] * rsqrtf(v2[o] + EPSBN);
    float mo = m2[o], bo = b2[o];

    int prS = half ? 11 : 0, prE = half ? 21 : 11;
    for (int pr = prS + mh; pr < prE; pr += 2) {
        int il = 2 * pr - r0 + (l15 & 1);
        for (int jt = 0; jt < 6; ++jt) {
            int j0 = (jt < 5) ? jt * 8 : 34;
            int jl = j0 + (l15 >> 1);
            const unsigned short* ab = lds + ((size_t)il * 46 + jl) * 32 + l4 * 8;
            f32x4 acc = {0.f, 0.f, 0.f, 0.f};
            #pragma unroll
            for (int ki = 0; ki < 5; ++ki)
                #pragma unroll
                for (int kj = 0; kj < 5; ++kj) {
                    bf16x8 av = *(const bf16x8*)(ab + (ki * 46 + kj) * 32);
                    acc = __builtin_amdgcn_mfma_f32_16x16x32_bf16(av, Bf[ki * 5 + kj], acc, 0, 0, 0);
                }
            const float* xs = xsq2 + ((size_t)b * H2C + 2 * pr) * H2C + (j0 + 2 * l4);
            float e0 = __expf(-GAMMA * (xs[0]       - 2.f * acc[0] + wq));
            float e1 = __expf(-GAMMA * (xs[H2C]     - 2.f * acc[1] + wq));
            float e2 = __expf(-GAMMA * (xs[1]       - 2.f * acc[2] + wq));
            float e3 = __expf(-GAMMA * (xs[H2C + 1] - 2.f * acc[3] + wq));
            float mx = fmaxf(fmaxf(e0, e1), fmaxf(e2, e3));
            float y = (mx - mo) * sc + bo;
            h2t[((size_t)b * 441 + pr * 21 + (j0 >> 1) + l4) * 64 + o] = f2bf(y);
        }
    }
}

// ------- wt1bf[n][p*64+o] = bf16(fc1w[n][o*441+p]) -------
__global__ __launch_bounds__(256) void k_trw(const float* __restrict__ in,
                                             unsigned short* __restrict__ out) {
    __shared__ float tile[64][65];
    int n = blockIdx.x, p0 = blockIdx.y * 64;
    int np = 441 - p0; if (np > 64) np = 64;
    for (int idx = threadIdx.x; idx < 64 * 64; idx += 256) {
        int o = idx >> 6, p = idx & 63;
        if (p < np) tile[o][p] = in[(size_t)n * FLAT + o * 441 + p0 + p];
    }
    __syncthreads();
    for (int idx = threadIdx.x; idx < 64 * 64; idx += 256) {
        int p = idx >> 6, o = idx & 63;
        if (p < np) out[(size_t)n * FLAT + (p0 + p) * 64 + o] = f2bf(tile[o][p]);
    }
}

// ------- FC1 MFMA: grid (63 ksegs, 4 nblocks x 2 mhalves), 256 thr -------
__global__ __launch_bounds__(256) void k_fc1m(const unsigned short* __restrict__ A,
                                              const unsigned short* __restrict__ Wt,
                                              float* __restrict__ part) {
    int lane = threadIdx.x & 63, w = threadIdx.x >> 6;
    int l15 = lane & 15, l4 = lane >> 4;
    int s = blockIdx.x;
    int nb = blockIdx.y >> 1, mh = blockIdx.y & 1;
    int n0 = nb * 64 + w * 16;
    int m0 = mh * 64;
    const unsigned short* wp = Wt + (size_t)(n0 + l15) * FLAT + l4 * 8;
    const unsigned short* ap = A + (size_t)(m0 + l15) * FLAT + l4 * 8;
    f32x4 acc[4];
    #pragma unroll
    for (int mf = 0; mf < 4; ++mf) acc[mf] = (f32x4){0.f, 0.f, 0.f, 0.f};
    int k0 = s * 448;
    #pragma unroll 2
    for (int kc = 0; kc < 14; ++kc) {
        int ko = k0 + kc * 32;
        bf16x8 Bf = *(const bf16x8*)(wp + ko);
        #pragma unroll
        for (int mf = 0; mf < 4; ++mf) {
            bf16x8 Af = *(const bf16x8*)(ap + (size_t)mf * 16 * FLAT + ko);
            acc[mf] = __builtin_amdgcn_mfma_f32_16x16x32_bf16(Af, Bf, acc[mf], 0, 0, 0);
        }
    }
    float* pp = part + (size_t)s * B_ * L1N;
    #pragma unroll
    for (int mf = 0; mf < 4; ++mf)
        #pragma unroll
        for (int r = 0; r < 4; ++r)
            pp[(size_t)(m0 + mf * 16 + l4 * 4 + r) * L1N + n0 + l15] = acc[mf][r];
}

// ---------------- FC1 reduce + bias + relu ----------------
__global__ void k_fc1red(const float* __restrict__ part, const float* __restrict__ bias,
                         float* __restrict__ fc1o) {
    int idx = blockIdx.x * blockDim.x + threadIdx.x;
    if (idx >= B_ * L1N) return;
    int o = idx & (L1N - 1);
    float s = 0.f;
    for (int ks = 0; ks < 63; ++ks) s += part[(size_t)ks * B_ * L1N + idx];
    fc1o[idx] = fmaxf(s + bias[o], 0.f);
}

// ---------------- FC2 + relu + log_softmax ----------------
__global__ void k_fc2(const float* __restrict__ a, const float* __restrict__ w,
                      const float* __restrict__ bias, float* __restrict__ out) {
    int b = blockIdx.x;
    int lane = threadIdx.x;  // 64
    __shared__ float z[NCLS];
    for (int j = 0; j < NCLS; ++j) {
        float p = 0.f;
        for (int k = lane; k < L1N; k += 64)
            p = fmaf(a[(size_t)b * L1N + k], w[(size_t)j * L1N + k], p);
        #pragma unroll
        for (int off = 32; off; off >>= 1) p += __shfl_down(p, off, 64);
        if (lane == 0) z[j] = fmaxf(p + bias[j], 0.f);
    }
    __syncthreads();
    if (lane == 0) {
        float mx = -1e30f;
        for (int j = 0; j < NCLS; ++j) mx = fmaxf(mx, z[j]);
        float s = 0.f;
        for (int j = 0; j < NCLS; ++j) s += expf(z[j] - mx);
        float l = logf(s);
        for (int j = 0; j < NCLS; ++j) out[(size_t)b * NCLS + j] = z[j] - mx - l;
    }
}

extern "C" void kernel_launch(void* const* d_in, const int* in_sizes, int n_in,
                              void* d_out, int out_size, void* d_ws, size_t ws_size,
                              hipStream_t stream) {
    const float* x    = (const float*)d_in[0];
    const float* w1   = (const float*)d_in[1];
    const float* w2   = (const float*)d_in[2];
    const float* bn1g = (const float*)d_in[3];
    const float* bn1b = (const float*)d_in[4];
    const float* bn1m = (const float*)d_in[5];
    const float* bn1v = (const float*)d_in[6];
    const float* bn2g = (const float*)d_in[7];
    const float* bn2b = (const float*)d_in[8];
    const float* bn2m = (const float*)d_in[9];
    const float* bn2v = (const float*)d_in[10];
    const float* fc1w = (const float*)d_in[11];
    const float* fc1b = (const float*)d_in[12];
    const float* fc2w = (const float*)d_in[13];
    const float* fc2b = (const float*)d_in[14];
    float* out = (float*)d_out;

    char* wsb = (char*)d_ws;
    unsigned short* h1t = (unsigned short*)wsb;  wsb += (size_t)B_ * 2116 * 32 * 2;     // 17.3 MB
    unsigned short* x8  = (unsigned short*)wsb;  wsb += (size_t)B_ * H0 * XW * 8 * 2;   // 20.4 MB
    float* ssum1 = (float*)wsb;                  wsb += (size_t)B_ * 9216 * 4;          // 4.7 MB
    float* xsq1  = (float*)wsb;                  wsb += (size_t)B_ * 92 * 92 * 4;       // 4.3 MB
    float* ssum  = (float*)wsb;                  wsb += (size_t)B_ * 2116 * 4;          // 1.1 MB
    float* xsq2  = (float*)wsb;                  wsb += (size_t)B_ * H2C * H2C * 4;     // 0.9 MB
    unsigned short* h2t = (unsigned short*)wsb;  wsb += (size_t)B_ * FLAT * 2;          // 7.2 MB
    unsigned short* wt1bf = (unsigned short*)wsb; wsb += (size_t)FLAT * L1N * 2;        // 14.4 MB
    float* part  = (float*)wsb;                  wsb += (size_t)63 * B_ * L1N * 4;      // 8.3 MB
    float* fc1o  = (float*)wsb;                  wsb += (size_t)B_ * L1N * 4;
    unsigned short* w2bf = (unsigned short*)wsb; wsb += (size_t)25 * 64 * 32 * 2;
    unsigned short* w1p8 = (unsigned short*)wsb; wsb += (size_t)28 * 32 * 8 * 2;
    float* wsq1 = (float*)wsb;                   wsb += 32 * 4;
    float* wsq2 = (float*)wsb;                   wsb += 64 * 4;

    k_prep<<<64, 256, 0, stream>>>(w1, w2, wsq1, wsq2, w2bf, w1p8);
    k_trw<<<dim3(L1N, 7), 256, 0, stream>>>(fc1w, wt1bf);
    k_x8<<<(B_ * H0 * XW + 255) / 256, 256, 0, stream>>>(x, x8);
    k_ssum1<<<(B_ * 9216 + 255) / 256, 256, 0, stream>>>(x, ssum1);
    k_xsq1b<<<(B_ * 92 * 92 + 255) / 256, 256, 0, stream>>>(ssum1, xsq1);
    k_conv1m<<<dim3(12, B_), 256, 0, stream>>>(
        x8, w1p8, xsq1, wsq1, bn1g, bn1b, bn1m, bn1v, h1t);
    k_ssum<<<(B_ * 2116 + 255) / 256, 256, 0, stream>>>(h1t, ssum);
    k_xsq2s<<<(B_ * H2C * H2C + 255) / 256, 256, 0, stream>>>(ssum, xsq2);
    k_conv2m<<<dim3(2, B_), 512, 0, stream>>>(
        h1t, w2bf, xsq2, wsq2, bn2g, bn2b, bn2m, bn2v, h2t);
    k_fc1m<<<dim3(63, 8), 256, 0, stream>>>(h2t, wt1bf, part);
    k_fc1red<<<(B_ * L1N + 255) / 256, 256, 0, stream>>>(part, fc1b, fc1o);
    k_fc2<<<B_, 64, 0, stream>>>(fc1o, fc2w, fc2b, out);
}